// Round 3
// baseline (2146.276 us; speedup 1.0000x reference)
//
#include <hip/hip_runtime.h>
#include <stdint.h>

typedef unsigned short u16;   // bf16 bits

#define B_   4
#define N_   4096
#define C_   1024
#define NT_  (B_*N_)          // 16384 rows
#define HW_  64               // H = W = 64

__device__ __forceinline__ float b2f(u16 s) {
    union { uint32_t u; float f; } x; x.u = ((uint32_t)s) << 16; return x.f;
}
__device__ __forceinline__ u16 f2b(float f) {
    union { float f; uint32_t u; } x; x.f = f;
    uint32_t u = x.u;
    return (u16)((u + 0x7FFFu + ((u >> 16) & 1u)) >> 16);   // RNE
}
__device__ __forceinline__ float lo2f(uint32_t u) {
    union { uint32_t u; float f; } x; x.u = u << 16; return x.f;
}
__device__ __forceinline__ float hi2f(uint32_t u) {
    union { uint32_t u; float f; } x; x.u = u & 0xFFFF0000u; return x.f;
}
__device__ __forceinline__ void unpack8(uint4 v, float* f) {
    f[0] = lo2f(v.x); f[1] = hi2f(v.x); f[2] = lo2f(v.y); f[3] = hi2f(v.y);
    f[4] = lo2f(v.z); f[5] = hi2f(v.z); f[6] = lo2f(v.w); f[7] = hi2f(v.w);
}

// ---------------------------------------------------------------------------
// Input format detector. If inputs are fp32, the LOW u16 of each word is
// random mantissa bits -> its "bf16 exponent" field is uniform over 0..255,
// so max over 2048 samples is >= 0x90 almost surely. Genuine bf16 N(0,1)
// data has exponent <= ~0x81. flag: 0 = bf16, 1 = fp32.
// ---------------------------------------------------------------------------
__global__ void detect_fmt(const u16* __restrict__ x, int* __restrict__ flag)
{
    __shared__ int smax[256];
    const int t = threadIdx.x;
    int m = 0;
    for (int i = t; i < 2048; i += 256) {
        int e = (x[2 * i] >> 7) & 0xFF;
        m = m > e ? m : e;
    }
    smax[t] = m;
    __syncthreads();
    for (int s = 128; s > 0; s >>= 1) {
        if (t < s) smax[t] = smax[t] > smax[t + s] ? smax[t] : smax[t + s];
        __syncthreads();
    }
    if (t == 0) flag[0] = (smax[0] >= 0x90) ? 1 : 0;
}

// ---------------------------------------------------------------------------
// GEMM, fp32 accumulate, dual input format. C[m, j] = sum_k A[m,k]*B[k, bcol0+j0+j]
// Tile 128x128, 256 threads, 8x8 microtile, K-tile 16.
// AEXT: A is an external input (consult fmt). CEXT: C store consults fmt.
// B and bias are always external. Internal tensors are always bf16.
// ---------------------------------------------------------------------------
template<int RELU, int BIAS, int AEXT, int CEXT>
__global__ __launch_bounds__(256)
void gemm_any(const void* __restrict__ A, const void* __restrict__ Bm,
              void* __restrict__ Cout, const void* __restrict__ bias,
              const int* __restrict__ flag,
              int M, int K, int ldb, int bcol0, int ldc)
{
    const int fmt = flag[0];
    __shared__ float As[16][128];
    __shared__ float Bs[16][128];
    const int t  = threadIdx.x;
    const int tx = t & 15, ty = t >> 4;
    const int m0 = blockIdx.y * 128;
    const int j0 = blockIdx.x * 128;

    const int la_row = t >> 1;          // 0..127
    const int la_k   = (t & 1) * 8;     // 0 or 8
    const int lb_k   = t >> 4;          // 0..15
    const int lb_j   = (t & 15) * 8;    // 0..120

    float acc[8][8];
    #pragma unroll
    for (int i = 0; i < 8; ++i)
        #pragma unroll
        for (int j = 0; j < 8; ++j) acc[i][j] = 0.f;

    for (int k0 = 0; k0 < K; k0 += 16) {
        float af[8], bfv[8];
        if (AEXT && fmt) {
            const float* ap = (const float*)A + (size_t)(m0 + la_row) * K + k0 + la_k;
            float4 a0 = *(const float4*)ap;
            float4 a1 = *(const float4*)(ap + 4);
            af[0] = a0.x; af[1] = a0.y; af[2] = a0.z; af[3] = a0.w;
            af[4] = a1.x; af[5] = a1.y; af[6] = a1.z; af[7] = a1.w;
        } else {
            uint4 av = *(const uint4*)((const u16*)A + (size_t)(m0 + la_row) * K + k0 + la_k);
            unpack8(av, af);
        }
        if (fmt) {
            const float* bp = (const float*)Bm + (size_t)(k0 + lb_k) * ldb + bcol0 + j0 + lb_j;
            float4 b0 = *(const float4*)bp;
            float4 b1 = *(const float4*)(bp + 4);
            bfv[0] = b0.x; bfv[1] = b0.y; bfv[2] = b0.z; bfv[3] = b0.w;
            bfv[4] = b1.x; bfv[5] = b1.y; bfv[6] = b1.z; bfv[7] = b1.w;
        } else {
            uint4 bv = *(const uint4*)((const u16*)Bm + (size_t)(k0 + lb_k) * ldb + bcol0 + j0 + lb_j);
            unpack8(bv, bfv);
        }
        __syncthreads();   // protect previous tile's reads
        #pragma unroll
        for (int i = 0; i < 8; ++i) As[la_k + i][la_row] = af[i];
        *(float4*)&Bs[lb_k][lb_j]     = make_float4(bfv[0], bfv[1], bfv[2], bfv[3]);
        *(float4*)&Bs[lb_k][lb_j + 4] = make_float4(bfv[4], bfv[5], bfv[6], bfv[7]);
        __syncthreads();
        #pragma unroll
        for (int kk = 0; kk < 16; ++kk) {
            float a[8], b[8];
            *(float4*)&a[0] = *(const float4*)&As[kk][ty * 8];
            *(float4*)&a[4] = *(const float4*)&As[kk][ty * 8 + 4];
            *(float4*)&b[0] = *(const float4*)&Bs[kk][tx * 8];
            *(float4*)&b[4] = *(const float4*)&Bs[kk][tx * 8 + 4];
            #pragma unroll
            for (int i = 0; i < 8; ++i)
                #pragma unroll
                for (int j = 0; j < 8; ++j)
                    acc[i][j] += a[i] * b[j];
        }
    }

    #pragma unroll
    for (int i = 0; i < 8; ++i) {
        const int m = m0 + ty * 8 + i;
        float vals[8];
        #pragma unroll
        for (int j = 0; j < 8; ++j) {
            float v = acc[i][j];
            if (BIAS) {
                const int bi = j0 + tx * 8 + j;
                v += fmt ? ((const float*)bias)[bi] : b2f(((const u16*)bias)[bi]);
            }
            if (RELU) v = fmaxf(v, 0.f) + 1e-6f;
            vals[j] = v;
        }
        if (CEXT && fmt) {
            float* cp = (float*)Cout + (size_t)m * ldc + j0 + tx * 8;
            *(float4*)cp       = make_float4(vals[0], vals[1], vals[2], vals[3]);
            *(float4*)(cp + 4) = make_float4(vals[4], vals[5], vals[6], vals[7]);
        } else {
            union { uint4 v; u16 s[8]; } o;
            #pragma unroll
            for (int j = 0; j < 8; ++j) o.s[j] = f2b(vals[j]);
            *(uint4*)((u16*)Cout + (size_t)m * ldc + j0 + tx * 8) = o.v;
        }
    }
}

// zero a float buffer
__global__ void zero_f32(float* p, int n) {
    int i = blockIdx.x * 256 + threadIdx.x;
    if (i < n) p[i] = 0.f;
}

// k_mean[b, c] = mean_n k[b, n, c]; atomic partial sums (km pre-zeroed)
__global__ __launch_bounds__(256)
void kmean_kernel(const u16* __restrict__ k, float* __restrict__ km)
{
    const int c  = blockIdx.x * 256 + threadIdx.x;  // 0..1023
    const int b  = blockIdx.y;
    const int nc = blockIdx.z;                      // 0..15
    const u16* p = k + ((size_t)b * N_ + nc * 256) * C_ + c;
    float s = 0.f;
    for (int n = 0; n < 256; ++n) s += b2f(p[(size_t)n * C_]);
    atomicAdd(&km[b * C_ + c], s * (1.0f / N_));
}

// kvh[bh, d*64+e] += (1/N) * sum_{n in chunk} k[b,n,h*64+d]*v[b,n,h*64+e]
// kvh pre-zeroed; grid (64 bh, 8 chunks)
__global__ __launch_bounds__(256)
void kv_atomic(const u16* __restrict__ k, const u16* __restrict__ v,
               float* __restrict__ kvh)
{
    __shared__ float kk[4][64];
    __shared__ float vv[4][64];
    const int bh = blockIdx.x;      // 0..63
    const int ch = blockIdx.y;      // 0..7
    const int b = bh >> 4, h = bh & 15;
    const int t = threadIdx.x;
    const int e = t & 63, d0 = (t >> 6) * 16;
    const int lr = t >> 6, lc = t & 63;
    const int n0 = ch * 512;
    float acc[16];
    #pragma unroll
    for (int i = 0; i < 16; ++i) acc[i] = 0.f;

    for (int nb = 0; nb < 512; nb += 4) {
        size_t base = ((size_t)(b * N_ + n0 + nb + lr)) * C_ + h * 64 + lc;
        float kf = b2f(k[base]);
        float vf = b2f(v[base]);
        __syncthreads();
        kk[lr][lc] = kf;
        vv[lr][lc] = vf;
        __syncthreads();
        #pragma unroll
        for (int r = 0; r < 4; ++r) {
            float ve = vv[r][e];
            #pragma unroll
            for (int i = 0; i < 16; ++i) acc[i] += kk[r][d0 + i] * ve;
        }
    }
    float* dst = kvh + (size_t)bh * 4096;
    #pragma unroll
    for (int i = 0; i < 16; ++i)
        atomicAdd(&dst[(d0 + i) * 64 + e], acc[i] * (1.0f / N_));
}

// att: y[b, n, h*64+e] = z_n * sum_d q[b,n,h*64+d] * kvh[bh, d, e]
// IN-PLACE SAFE over q: each q element is read only by the block that
// rewrites it, and is staged to LDS before any global write.
__global__ __launch_bounds__(256)
void att_kernel(const u16* __restrict__ q, const float* __restrict__ kvh,
                const float* __restrict__ kmean, u16* __restrict__ y)
{
    __shared__ float kvs[64 * 64];
    __shared__ float qs[64 * 65];
    __shared__ float kmv[64];
    __shared__ float zs[64];
    const int bh = blockIdx.y;
    const int b = bh >> 4, h = bh & 15;
    const int n0 = blockIdx.x * 64;
    const int t = threadIdx.x;

    const float* kvsrc = kvh + (size_t)bh * 4096;
    for (int i = t; i < 4096; i += 256) kvs[i] = kvsrc[i];
    if (t < 64) kmv[t] = kmean[b * C_ + h * 64 + t];
    for (int i = t; i < 4096; i += 256) {
        int r = i >> 6, cq = i & 63;
        qs[r * 65 + cq] = b2f(q[((size_t)(b * N_ + n0 + r)) * C_ + h * 64 + cq]);
    }
    __syncthreads();
    if (t < 64) {
        float s = 1e-6f;
        #pragma unroll
        for (int d = 0; d < 64; ++d) s += qs[t * 65 + d] * kmv[d];
        zs[t] = 1.0f / s;
    }
    __syncthreads();
    const int e = t & 63, rg = t >> 6;
    for (int rr = 0; rr < 16; ++rr) {
        int r = rg * 16 + rr;
        float acc = 0.f;
        #pragma unroll
        for (int d = 0; d < 64; ++d) acc += qs[r * 65 + d] * kvs[d * 64 + e];
        y[((size_t)(b * N_ + n0 + r)) * C_ + h * 64 + e] = f2b(acc * zs[r]);
    }
}

// depthwise 5x5 conv over v (B*h images, 64 channels, 64x64), add into y
__global__ __launch_bounds__(256)
void conv_add(const u16* __restrict__ v, const void* __restrict__ w,
              const void* __restrict__ wb, u16* __restrict__ y,
              const int* __restrict__ flag)
{
    __shared__ float wl[64 * 25];
    __shared__ float bl[64];
    const int fmt = flag[0];
    const int t = threadIdx.x;
    for (int i = t; i < 1600; i += 256)
        wl[i] = fmt ? ((const float*)w)[i] : b2f(((const u16*)w)[i]);
    if (t < 64)
        bl[t] = fmt ? ((const float*)wb)[t] : b2f(((const u16*)wb)[t]);
    __syncthreads();

    const size_t idx = (size_t)blockIdx.x * 256 + t;   // (b, n, cc) flat
    const int cc = (int)(idx & 1023);
    const int n  = (int)((idx >> 10) & 4095);
    const int b  = (int)(idx >> 22);
    const int c  = cc & 63;
    const int yp = n >> 6, xp = n & 63;

    float val = bl[c];
    #pragma unroll
    for (int dy = 0; dy < 5; ++dy) {
        const int yy = yp + dy - 2;
        if (yy < 0 || yy >= HW_) continue;
        #pragma unroll
        for (int dx = 0; dx < 5; ++dx) {
            const int xx = xp + dx - 2;
            if (xx < 0 || xx >= HW_) continue;
            val += wl[c * 25 + dy * 5 + dx] *
                   b2f(v[((size_t)(b * N_) + yy * HW_ + xx) * C_ + cc]);
        }
    }
    float a = b2f(y[idx]);
    y[idx] = f2b(a + val);
}

extern "C" void kernel_launch(void* const* d_in, const int* in_sizes, int n_in,
                              void* d_out, int out_size, void* d_ws, size_t ws_size,
                              hipStream_t stream)
{
    const void* x     = d_in[0];
    const void* Wq    = d_in[1];
    const void* Wkv   = d_in[2];
    const void* Wproj = d_in[3];
    const void* bproj = d_in[4];
    const void* dwc_w = d_in[5];
    const void* dwc_b = d_in[6];

    // ---- workspace layout (total ~34.7 MiB) ----
    // [0, 32Mi)          : v (bf16), later reused for the y copy
    // [32Mi, +16Ki)      : kmean (fp32)
    // [32Mi+16Ki, +1Mi)  : kvh   (fp32)
    // [.. +4B]           : fmt flag
    // k, q, y all live in d_out (sequenced: k dead -> q -> y in-place).
    char* ws = (char*)d_ws;
    const size_t MI = 1024 * 1024;
    u16*   vbuf  = (u16*)ws;
    float* kmean = (float*)(ws + 32 * MI);
    float* kvh   = (float*)(ws + 32 * MI + 16 * 1024);
    int*   flag  = (int*)(ws + 32 * MI + 16 * 1024 + 1 * MI);
    u16*   kq    = (u16*)d_out;          // k, then q, then y (in-place)
    u16*   ybuf  = (u16*)ws;             // y after D2D copy (v dead by then)

    detect_fmt<<<1, 256, 0, stream>>>((const u16*)x, flag);
    zero_f32<<<dim3(1040), 256, 0, stream>>>(kmean, 4096 + 262144);  // kmean+kvh contiguous

    // v = x@Wkv[:, C:] ; k = relu(x@Wkv[:, :C])+eps (k -> d_out)
    gemm_any<0, 0, 1, 0><<<dim3(8, 128), 256, 0, stream>>>(x, Wkv, vbuf, nullptr, flag, NT_, C_, 2 * C_, C_, C_);
    gemm_any<1, 0, 1, 0><<<dim3(8, 128), 256, 0, stream>>>(x, Wkv, kq,   nullptr, flag, NT_, C_, 2 * C_, 0,  C_);

    kmean_kernel<<<dim3(4, B_, 16), 256, 0, stream>>>(kq, kmean);
    kv_atomic<<<dim3(64, 8), 256, 0, stream>>>(kq, vbuf, kvh);

    // q = relu(x@Wq)+eps -> d_out (k dead now)
    gemm_any<1, 0, 1, 0><<<dim3(8, 128), 256, 0, stream>>>(x, Wq, kq, nullptr, flag, NT_, C_, C_, 0, C_);

    // y = att(q) in-place in d_out; then y += conv(v)
    att_kernel<<<dim3(64, 64), 256, 0, stream>>>(kq, kvh, kmean, kq);
    conv_add<<<dim3(65536), 256, 0, stream>>>(vbuf, dwc_w, dwc_b, kq, flag);

    // move y to ws (v dead) so the projection GEMM can write d_out race-free
    hipMemcpyAsync(ws, d_out, (size_t)NT_ * C_ * sizeof(u16), hipMemcpyDeviceToDevice, stream);

    // out = y @ Wproj + bproj (store format per flag)
    gemm_any<0, 1, 0, 1><<<dim3(8, 128), 256, 0, stream>>>(ybuf, Wproj, d_out, bproj, flag, NT_, C_, C_, 0, C_);
}

// Round 4
// 977.193 us; speedup vs baseline: 2.1964x; 2.1964x over previous
//
#include <hip/hip_runtime.h>
#include <stdint.h>

typedef unsigned short u16;   // bf16 bits

#define B_   4
#define N_   4096
#define C_   1024
#define NT_  (B_*N_)          // 16384 rows
#define HW_  64               // H = W = 64

typedef __attribute__((ext_vector_type(8))) short bf16x8;
typedef __attribute__((ext_vector_type(4))) float f32x4;

__device__ __forceinline__ float b2f(u16 s) {
    union { uint32_t u; float f; } x; x.u = ((uint32_t)s) << 16; return x.f;
}
__device__ __forceinline__ u16 f2b(float f) {
    union { float f; uint32_t u; } x; x.f = f;
    uint32_t u = x.u;
    return (u16)((u + 0x7FFFu + ((u >> 16) & 1u)) >> 16);   // RNE
}
__device__ __forceinline__ float lo2f(uint32_t u) {
    union { uint32_t u; float f; } x; x.u = u << 16; return x.f;
}
__device__ __forceinline__ float hi2f(uint32_t u) {
    union { uint32_t u; float f; } x; x.u = u & 0xFFFF0000u; return x.f;
}
__device__ __forceinline__ void unpack8(uint4 v, float* f) {
    f[0] = lo2f(v.x); f[1] = hi2f(v.x); f[2] = lo2f(v.y); f[3] = hi2f(v.y);
    f[4] = lo2f(v.z); f[5] = hi2f(v.z); f[6] = lo2f(v.w); f[7] = hi2f(v.w);
}

// ---------------------------------------------------------------------------
// Input format detector (0 = bf16, 1 = fp32); see R2 notes.
// ---------------------------------------------------------------------------
__global__ void detect_fmt(const u16* __restrict__ x, int* __restrict__ flag)
{
    __shared__ int smax[256];
    const int t = threadIdx.x;
    int m = 0;
    for (int i = t; i < 2048; i += 256) {
        int e = (x[2 * i] >> 7) & 0xFF;
        m = m > e ? m : e;
    }
    smax[t] = m;
    __syncthreads();
    for (int s = 128; s > 0; s >>= 1) {
        if (t < s) smax[t] = smax[t] > smax[t + s] ? smax[t] : smax[t + s];
        __syncthreads();
    }
    if (t == 0) flag[0] = (smax[0] >= 0x90) ? 1 : 0;
}

__global__ void zero_f32(float* p, int n) {
    int i = blockIdx.x * 256 + threadIdx.x;
    if (i < n) p[i] = 0.f;
}

// ---------------------------------------------------------------------------
// Weight transpose: WT[n, k] = W[k, col0+n] as bf16. W fmt per flag.
// Grid (Ncols/64, Kdim/64), block 256.
// ---------------------------------------------------------------------------
__global__ __launch_bounds__(256)
void transpose_w(const void* __restrict__ W, u16* __restrict__ WT,
                 const int* __restrict__ flag, int ldw, int col0, int Kdim)
{
    __shared__ u16 tile[64][65];
    const int fmt = flag[0];
    const int n0 = blockIdx.x * 64, k0 = blockIdx.y * 64;
    const int t = threadIdx.x;
    const int c = t & 63, rg = t >> 6;
    #pragma unroll 4
    for (int i = 0; i < 16; ++i) {
        int r = rg * 16 + i;
        size_t gi = (size_t)(k0 + r) * ldw + col0 + n0 + c;
        tile[r][c] = fmt ? f2b(((const float*)W)[gi]) : ((const u16*)W)[gi];
    }
    __syncthreads();
    #pragma unroll 4
    for (int i = 0; i < 16; ++i) {
        int r = rg * 16 + i;
        WT[(size_t)(n0 + r) * Kdim + k0 + c] = tile[c][r];
    }
}

// ---------------------------------------------------------------------------
// MFMA GEMM: C[m, j] = sum_k A[m,k] * BT[j,k]   (BT: n-major bf16)
// 128x128 tile, 4 waves (2x2), 4x4 x mfma_f32_16x16x32_bf16 per wave.
// global_load_lds(16B) staging; XOR k-segment swizzle for bank-conflict-free
// b128 fragment reads. AEXT: A may be fp32 (per flag) -> VGPR convert path.
// ---------------------------------------------------------------------------
template<int RELU, int BIAS, int AEXT, int CEXT>
__global__ __launch_bounds__(256)
void gemm_mfma(const void* __restrict__ A, const u16* __restrict__ BT,
               void* __restrict__ Cout, const void* __restrict__ bias,
               const int* __restrict__ flag, int K, int ldc)
{
    __shared__ u16 As[128 * 32];
    __shared__ u16 Bs[128 * 32];
    const int fmt = flag[0];
    const int t    = threadIdx.x;
    const int lane = t & 63;
    const int w    = t >> 6;          // wave 0..3
    const int wm   = w >> 1, wn = w & 1;
    const int quad = lane >> 4;       // 0..3
    const int l16  = lane & 15;
    const int m0 = blockIdx.y * 128;
    const int j0 = blockIdx.x * 128;

    // staging: lane -> row (lane>>2) within 16-row group, k-segment slot lane&3,
    // fetches global segment slot ^ ((row>>1)&3)  (bank-conflict swizzle)
    const int srow = lane >> 2;
    const int gseg = ((lane & 3) ^ ((lane >> 3) & 3)) * 8;

    f32x4 acc[4][4] = {};

    for (int k0 = 0; k0 < K; k0 += 32) {
        if (AEXT && fmt) {
            #pragma unroll
            for (int i = 0; i < 2; ++i) {
                const int r0 = w * 32 + i * 16;
                const float* gp = (const float*)A + (size_t)(m0 + r0 + srow) * K + k0 + gseg;
                float4 f0 = *(const float4*)gp;
                float4 f1 = *(const float4*)(gp + 4);
                union { bf16x8 v; u16 s[8]; } o;
                o.s[0] = f2b(f0.x); o.s[1] = f2b(f0.y); o.s[2] = f2b(f0.z); o.s[3] = f2b(f0.w);
                o.s[4] = f2b(f1.x); o.s[5] = f2b(f1.y); o.s[6] = f2b(f1.z); o.s[7] = f2b(f1.w);
                *(bf16x8*)&As[(r0 + srow) * 32 + (lane & 3) * 8] = o.v;
            }
        } else {
            #pragma unroll
            for (int i = 0; i < 2; ++i) {
                const int r0 = w * 32 + i * 16;
                const u16* gp = (const u16*)A + (size_t)(m0 + r0 + srow) * K + k0 + gseg;
                __builtin_amdgcn_global_load_lds(
                    (const __attribute__((address_space(1))) void*)gp,
                    (__attribute__((address_space(3))) void*)&As[r0 * 32], 16, 0, 0);
            }
        }
        #pragma unroll
        for (int i = 0; i < 2; ++i) {
            const int r0 = w * 32 + i * 16;
            const u16* gp = BT + (size_t)(j0 + r0 + srow) * K + k0 + gseg;
            __builtin_amdgcn_global_load_lds(
                (const __attribute__((address_space(1))) void*)gp,
                (__attribute__((address_space(3))) void*)&Bs[r0 * 32], 16, 0, 0);
        }
        __syncthreads();

        bf16x8 af[4], bfr[4];
        #pragma unroll
        for (int mt = 0; mt < 4; ++mt) {
            const int r = wm * 64 + mt * 16 + l16;
            const int slot = quad ^ ((r >> 1) & 3);
            af[mt] = *(const bf16x8*)&As[r * 32 + slot * 8];
        }
        #pragma unroll
        for (int nt = 0; nt < 4; ++nt) {
            const int r = wn * 64 + nt * 16 + l16;
            const int slot = quad ^ ((r >> 1) & 3);
            bfr[nt] = *(const bf16x8*)&Bs[r * 32 + slot * 8];
        }
        #pragma unroll
        for (int mt = 0; mt < 4; ++mt)
            #pragma unroll
            for (int nt = 0; nt < 4; ++nt)
                acc[mt][nt] = __builtin_amdgcn_mfma_f32_16x16x32_bf16(
                    af[mt], bfr[nt], acc[mt][nt], 0, 0, 0);
        __syncthreads();
    }

    // C/D layout: col = lane&15, row = quad*4 + reg
    #pragma unroll
    for (int mt = 0; mt < 4; ++mt) {
        #pragma unroll
        for (int nt = 0; nt < 4; ++nt) {
            const int col = j0 + wn * 64 + nt * 16 + l16;
            float bv = 0.f;
            if (BIAS) bv = fmt ? ((const float*)bias)[col] : b2f(((const u16*)bias)[col]);
            #pragma unroll
            for (int r = 0; r < 4; ++r) {
                const int row = m0 + wm * 64 + mt * 16 + quad * 4 + r;
                float v = acc[mt][nt][r];
                if (BIAS) v += bv;
                if (RELU) v = fmaxf(v, 0.f) + 1e-6f;
                if (CEXT && fmt) ((float*)Cout)[(size_t)row * ldc + col] = v;
                else             ((u16*)Cout)[(size_t)row * ldc + col] = f2b(v);
            }
        }
    }
}

// ---------------------------------------------------------------------------
// Fallback VALU GEMM (proven in R2) — used only if ws_size is too small.
// ---------------------------------------------------------------------------
template<int RELU, int BIAS, int AEXT, int CEXT>
__global__ __launch_bounds__(256)
void gemm_any(const void* __restrict__ A, const void* __restrict__ Bm,
              void* __restrict__ Cout, const void* __restrict__ bias,
              const int* __restrict__ flag,
              int M, int K, int ldb, int bcol0, int ldc)
{
    const int fmt = flag[0];
    __shared__ float As[16][128];
    __shared__ float Bs[16][128];
    const int t  = threadIdx.x;
    const int tx = t & 15, ty = t >> 4;
    const int m0 = blockIdx.y * 128;
    const int j0 = blockIdx.x * 128;
    const int la_row = t >> 1;
    const int la_k   = (t & 1) * 8;
    const int lb_k   = t >> 4;
    const int lb_j   = (t & 15) * 8;

    float acc[8][8];
    #pragma unroll
    for (int i = 0; i < 8; ++i)
        #pragma unroll
        for (int j = 0; j < 8; ++j) acc[i][j] = 0.f;

    for (int k0 = 0; k0 < K; k0 += 16) {
        float af[8], bfv[8];
        if (AEXT && fmt) {
            const float* ap = (const float*)A + (size_t)(m0 + la_row) * K + k0 + la_k;
            float4 a0 = *(const float4*)ap;
            float4 a1 = *(const float4*)(ap + 4);
            af[0] = a0.x; af[1] = a0.y; af[2] = a0.z; af[3] = a0.w;
            af[4] = a1.x; af[5] = a1.y; af[6] = a1.z; af[7] = a1.w;
        } else {
            uint4 av = *(const uint4*)((const u16*)A + (size_t)(m0 + la_row) * K + k0 + la_k);
            unpack8(av, af);
        }
        if (fmt) {
            const float* bp = (const float*)Bm + (size_t)(k0 + lb_k) * ldb + bcol0 + j0 + lb_j;
            float4 b0 = *(const float4*)bp;
            float4 b1 = *(const float4*)(bp + 4);
            bfv[0] = b0.x; bfv[1] = b0.y; bfv[2] = b0.z; bfv[3] = b0.w;
            bfv[4] = b1.x; bfv[5] = b1.y; bfv[6] = b1.z; bfv[7] = b1.w;
        } else {
            uint4 bv = *(const uint4*)((const u16*)Bm + (size_t)(k0 + lb_k) * ldb + bcol0 + j0 + lb_j);
            unpack8(bv, bfv);
        }
        __syncthreads();
        #pragma unroll
        for (int i = 0; i < 8; ++i) As[la_k + i][la_row] = af[i];
        *(float4*)&Bs[lb_k][lb_j]     = make_float4(bfv[0], bfv[1], bfv[2], bfv[3]);
        *(float4*)&Bs[lb_k][lb_j + 4] = make_float4(bfv[4], bfv[5], bfv[6], bfv[7]);
        __syncthreads();
        #pragma unroll
        for (int kk = 0; kk < 16; ++kk) {
            float a[8], b[8];
            *(float4*)&a[0] = *(const float4*)&As[kk][ty * 8];
            *(float4*)&a[4] = *(const float4*)&As[kk][ty * 8 + 4];
            *(float4*)&b[0] = *(const float4*)&Bs[kk][tx * 8];
            *(float4*)&b[4] = *(const float4*)&Bs[kk][tx * 8 + 4];
            #pragma unroll
            for (int i = 0; i < 8; ++i)
                #pragma unroll
                for (int j = 0; j < 8; ++j)
                    acc[i][j] += a[i] * b[j];
        }
    }

    #pragma unroll
    for (int i = 0; i < 8; ++i) {
        const int m = m0 + ty * 8 + i;
        float vals[8];
        #pragma unroll
        for (int j = 0; j < 8; ++j) {
            float v = acc[i][j];
            if (BIAS) {
                const int bi = j0 + tx * 8 + j;
                v += fmt ? ((const float*)bias)[bi] : b2f(((const u16*)bias)[bi]);
            }
            if (RELU) v = fmaxf(v, 0.f) + 1e-6f;
            vals[j] = v;
        }
        if (CEXT && fmt) {
            float* cp = (float*)Cout + (size_t)m * ldc + j0 + tx * 8;
            *(float4*)cp       = make_float4(vals[0], vals[1], vals[2], vals[3]);
            *(float4*)(cp + 4) = make_float4(vals[4], vals[5], vals[6], vals[7]);
        } else {
            union { uint4 v; u16 s[8]; } o;
            #pragma unroll
            for (int j = 0; j < 8; ++j) o.s[j] = f2b(vals[j]);
            *(uint4*)((u16*)Cout + (size_t)m * ldc + j0 + tx * 8) = o.v;
        }
    }
}

// k_mean[b, c] = mean_n k[b, n, c]
__global__ __launch_bounds__(256)
void kmean_kernel(const u16* __restrict__ k, float* __restrict__ km)
{
    const int c  = blockIdx.x * 256 + threadIdx.x;
    const int b  = blockIdx.y;
    const int nc = blockIdx.z;
    const u16* p = k + ((size_t)b * N_ + nc * 256) * C_ + c;
    float s = 0.f;
    for (int n = 0; n < 256; ++n) s += b2f(p[(size_t)n * C_]);
    atomicAdd(&km[b * C_ + c], s * (1.0f / N_));
}

// kvh[bh, d*64+e] += (1/N) * sum_{n in chunk} k*v
__global__ __launch_bounds__(256)
void kv_atomic(const u16* __restrict__ k, const u16* __restrict__ v,
               float* __restrict__ kvh)
{
    __shared__ float kk[4][64];
    __shared__ float vv[4][64];
    const int bh = blockIdx.x;
    const int ch = blockIdx.y;
    const int b = bh >> 4, h = bh & 15;
    const int t = threadIdx.x;
    const int e = t & 63, d0 = (t >> 6) * 16;
    const int lr = t >> 6, lc = t & 63;
    const int n0 = ch * 512;
    float acc[16];
    #pragma unroll
    for (int i = 0; i < 16; ++i) acc[i] = 0.f;

    for (int nb = 0; nb < 512; nb += 4) {
        size_t base = ((size_t)(b * N_ + n0 + nb + lr)) * C_ + h * 64 + lc;
        float kf = b2f(k[base]);
        float vf = b2f(v[base]);
        __syncthreads();
        kk[lr][lc] = kf;
        vv[lr][lc] = vf;
        __syncthreads();
        #pragma unroll
        for (int r = 0; r < 4; ++r) {
            float ve = vv[r][e];
            #pragma unroll
            for (int i = 0; i < 16; ++i) acc[i] += kk[r][d0 + i] * ve;
        }
    }
    float* dst = kvh + (size_t)bh * 4096;
    #pragma unroll
    for (int i = 0; i < 16; ++i)
        atomicAdd(&dst[(d0 + i) * 64 + e], acc[i] * (1.0f / N_));
}

// att (in-place safe over q; see R2)
__global__ __launch_bounds__(256)
void att_kernel(const u16* __restrict__ q, const float* __restrict__ kvh,
                const float* __restrict__ kmean, u16* __restrict__ y)
{
    __shared__ float kvs[64 * 64];
    __shared__ float qs[64 * 65];
    __shared__ float kmv[64];
    __shared__ float zs[64];
    const int bh = blockIdx.y;
    const int b = bh >> 4, h = bh & 15;
    const int n0 = blockIdx.x * 64;
    const int t = threadIdx.x;

    const float* kvsrc = kvh + (size_t)bh * 4096;
    for (int i = t; i < 4096; i += 256) kvs[i] = kvsrc[i];
    if (t < 64) kmv[t] = kmean[b * C_ + h * 64 + t];
    for (int i = t; i < 4096; i += 256) {
        int r = i >> 6, cq = i & 63;
        qs[r * 65 + cq] = b2f(q[((size_t)(b * N_ + n0 + r)) * C_ + h * 64 + cq]);
    }
    __syncthreads();
    if (t < 64) {
        float s = 1e-6f;
        #pragma unroll
        for (int d = 0; d < 64; ++d) s += qs[t * 65 + d] * kmv[d];
        zs[t] = 1.0f / s;
    }
    __syncthreads();
    const int e = t & 63, rg = t >> 6;
    for (int rr = 0; rr < 16; ++rr) {
        int r = rg * 16 + rr;
        float acc = 0.f;
        #pragma unroll
        for (int d = 0; d < 64; ++d) acc += qs[r * 65 + d] * kvs[d * 64 + e];
        y[((size_t)(b * N_ + n0 + r)) * C_ + h * 64 + e] = f2b(acc * zs[r]);
    }
}

// depthwise 5x5 conv over v, add into y
__global__ __launch_bounds__(256)
void conv_add(const u16* __restrict__ v, const void* __restrict__ w,
              const void* __restrict__ wb, u16* __restrict__ y,
              const int* __restrict__ flag)
{
    __shared__ float wl[64 * 25];
    __shared__ float bl[64];
    const int fmt = flag[0];
    const int t = threadIdx.x;
    for (int i = t; i < 1600; i += 256)
        wl[i] = fmt ? ((const float*)w)[i] : b2f(((const u16*)w)[i]);
    if (t < 64)
        bl[t] = fmt ? ((const float*)wb)[t] : b2f(((const u16*)wb)[t]);
    __syncthreads();

    const size_t idx = (size_t)blockIdx.x * 256 + t;
    const int cc = (int)(idx & 1023);
    const int n  = (int)((idx >> 10) & 4095);
    const int b  = (int)(idx >> 22);
    const int c  = cc & 63;
    const int yp = n >> 6, xp = n & 63;

    float val = bl[c];
    #pragma unroll
    for (int dy = 0; dy < 5; ++dy) {
        const int yy = yp + dy - 2;
        if (yy < 0 || yy >= HW_) continue;
        #pragma unroll
        for (int dx = 0; dx < 5; ++dx) {
            const int xx = xp + dx - 2;
            if (xx < 0 || xx >= HW_) continue;
            val += wl[c * 25 + dy * 5 + dx] *
                   b2f(v[((size_t)(b * N_) + yy * HW_ + xx) * C_ + cc]);
        }
    }
    float a = b2f(y[idx]);
    y[idx] = f2b(a + val);
}

extern "C" void kernel_launch(void* const* d_in, const int* in_sizes, int n_in,
                              void* d_out, int out_size, void* d_ws, size_t ws_size,
                              hipStream_t stream)
{
    const void* x     = d_in[0];
    const void* Wq    = d_in[1];
    const void* Wkv   = d_in[2];
    const void* Wproj = d_in[3];
    const void* bproj = d_in[4];
    const void* dwc_w = d_in[5];
    const void* dwc_b = d_in[6];

    char* ws = (char*)d_ws;
    const size_t MI = 1024 * 1024;
    const size_t NEED_FAST = 35 * MI + 17 * 1024;

    if (ws_size >= NEED_FAST) {
        // ---- fast path (MFMA) ----
        // [0,32Mi) v (later ybuf) | [32Mi,34Mi) WT | [34Mi,35Mi) kvh |
        // [35Mi,+16Ki) kmean | flag
        u16*   vbuf  = (u16*)ws;
        u16*   WT    = (u16*)(ws + 32 * MI);
        float* kvh   = (float*)(ws + 34 * MI);
        float* kmean = (float*)(ws + 35 * MI);
        int*   flag  = (int*)(ws + 35 * MI + 16 * 1024);
        u16*   kq    = (u16*)d_out;
        u16*   ybuf  = (u16*)ws;

        detect_fmt<<<1, 256, 0, stream>>>((const u16*)x, flag);
        zero_f32<<<dim3(1040), 256, 0, stream>>>(kvh, 266240);   // kvh + kmean contiguous

        // v = x @ Wkv[:, C:]
        transpose_w<<<dim3(16, 16), 256, 0, stream>>>(Wkv, WT, flag, 2 * C_, C_, C_);
        gemm_mfma<0, 0, 1, 0><<<dim3(8, 128), 256, 0, stream>>>(x, WT, vbuf, nullptr, flag, C_, C_);
        // k = relu(x @ Wkv[:, :C]) + eps  -> d_out
        transpose_w<<<dim3(16, 16), 256, 0, stream>>>(Wkv, WT, flag, 2 * C_, 0, C_);
        gemm_mfma<1, 0, 1, 0><<<dim3(8, 128), 256, 0, stream>>>(x, WT, kq, nullptr, flag, C_, C_);

        kmean_kernel<<<dim3(4, B_, 16), 256, 0, stream>>>(kq, kmean);
        kv_atomic<<<dim3(64, 8), 256, 0, stream>>>(kq, vbuf, kvh);

        // q = relu(x @ Wq) + eps -> d_out (k dead)
        transpose_w<<<dim3(16, 16), 256, 0, stream>>>(Wq, WT, flag, C_, 0, C_);
        gemm_mfma<1, 0, 1, 0><<<dim3(8, 128), 256, 0, stream>>>(x, WT, kq, nullptr, flag, C_, C_);

        att_kernel<<<dim3(64, 64), 256, 0, stream>>>(kq, kvh, kmean, kq);
        conv_add<<<dim3(65536), 256, 0, stream>>>(vbuf, dwc_w, dwc_b, kq, flag);

        // move y into ws (v dead), then out = y @ Wproj + bproj
        hipMemcpyAsync(ws, d_out, (size_t)NT_ * C_ * sizeof(u16), hipMemcpyDeviceToDevice, stream);
        transpose_w<<<dim3(16, 16), 256, 0, stream>>>(Wproj, WT, flag, C_, 0, C_);
        gemm_mfma<0, 1, 0, 1><<<dim3(8, 128), 256, 0, stream>>>(ybuf, WT, d_out, bproj, flag, C_, C_);
    } else {
        // ---- fallback path (proven R2) ----
        u16*   vbuf  = (u16*)ws;
        float* kmean = (float*)(ws + 32 * MI);
        float* kvh   = (float*)(ws + 32 * MI + 16 * 1024);
        int*   flag  = (int*)(ws + 32 * MI + 16 * 1024 + 1 * MI);
        u16*   kq    = (u16*)d_out;
        u16*   ybuf  = (u16*)ws;

        detect_fmt<<<1, 256, 0, stream>>>((const u16*)x, flag);
        zero_f32<<<dim3(1040), 256, 0, stream>>>(kmean, 266240);

        gemm_any<0, 0, 1, 0><<<dim3(8, 128), 256, 0, stream>>>(x, Wkv, vbuf, nullptr, flag, NT_, C_, 2 * C_, C_, C_);
        gemm_any<1, 0, 1, 0><<<dim3(8, 128), 256, 0, stream>>>(x, Wkv, kq,   nullptr, flag, NT_, C_, 2 * C_, 0,  C_);

        kmean_kernel<<<dim3(4, B_, 16), 256, 0, stream>>>(kq, kmean);
        kv_atomic<<<dim3(64, 8), 256, 0, stream>>>(kq, vbuf, kvh);

        gemm_any<1, 0, 1, 0><<<dim3(8, 128), 256, 0, stream>>>(x, Wq, kq, nullptr, flag, NT_, C_, C_, 0, C_);

        att_kernel<<<dim3(64, 64), 256, 0, stream>>>(kq, kvh, kmean, kq);
        conv_add<<<dim3(65536), 256, 0, stream>>>(vbuf, dwc_w, dwc_b, kq, flag);

        hipMemcpyAsync(ws, d_out, (size_t)NT_ * C_ * sizeof(u16), hipMemcpyDeviceToDevice, stream);
        gemm_any<0, 1, 0, 1><<<dim3(8, 128), 256, 0, stream>>>(ybuf, Wproj, d_out, bproj, flag, NT_, C_, C_, 0, C_);
    }
}

// Round 5
// 779.078 us; speedup vs baseline: 2.7549x; 1.2543x over previous
//
#include <hip/hip_runtime.h>
#include <stdint.h>

typedef unsigned short u16;   // bf16 bits

#define B_   4
#define N_   4096
#define C_   1024
#define NT_  (B_*N_)          // 16384 rows
#define HW_  64               // H = W = 64

typedef __attribute__((ext_vector_type(8))) short bf16x8;
typedef __attribute__((ext_vector_type(4))) float f32x4;

__device__ __forceinline__ float b2f(u16 s) {
    union { uint32_t u; float f; } x; x.u = ((uint32_t)s) << 16; return x.f;
}
__device__ __forceinline__ u16 f2b(float f) {
    union { float f; uint32_t u; } x; x.f = f;
    uint32_t u = x.u;
    return (u16)((u + 0x7FFFu + ((u >> 16) & 1u)) >> 16);   // RNE
}
__device__ __forceinline__ float lo2f(uint32_t u) {
    union { uint32_t u; float f; } x; x.u = u << 16; return x.f;
}
__device__ __forceinline__ float hi2f(uint32_t u) {
    union { uint32_t u; float f; } x; x.u = u & 0xFFFF0000u; return x.f;
}
__device__ __forceinline__ void unpack8(uint4 v, float* f) {
    f[0] = lo2f(v.x); f[1] = hi2f(v.x); f[2] = lo2f(v.y); f[3] = hi2f(v.y);
    f[4] = lo2f(v.z); f[5] = hi2f(v.z); f[6] = lo2f(v.w); f[7] = hi2f(v.w);
}

// ---------------------------------------------------------------------------
// Input format detector (0 = bf16, 1 = fp32); see R2 notes.
// ---------------------------------------------------------------------------
__global__ void detect_fmt(const u16* __restrict__ x, int* __restrict__ flag)
{
    __shared__ int smax[256];
    const int t = threadIdx.x;
    int m = 0;
    for (int i = t; i < 2048; i += 256) {
        int e = (x[2 * i] >> 7) & 0xFF;
        m = m > e ? m : e;
    }
    smax[t] = m;
    __syncthreads();
    for (int s = 128; s > 0; s >>= 1) {
        if (t < s) smax[t] = smax[t] > smax[t + s] ? smax[t] : smax[t + s];
        __syncthreads();
    }
    if (t == 0) flag[0] = (smax[0] >= 0x90) ? 1 : 0;
}

__global__ void zero_f32(float* p, int n) {
    int i = blockIdx.x * 256 + threadIdx.x;
    if (i < n) p[i] = 0.f;
}

// ---------------------------------------------------------------------------
// Weight transpose: WT[n, k] = W[k, col0+n] as bf16. W fmt per flag.
// ---------------------------------------------------------------------------
__global__ __launch_bounds__(256)
void transpose_w(const void* __restrict__ W, u16* __restrict__ WT,
                 const int* __restrict__ flag, int ldw, int col0, int Kdim)
{
    __shared__ u16 tile[64][65];
    const int fmt = flag[0];
    const int n0 = blockIdx.x * 64, k0 = blockIdx.y * 64;
    const int t = threadIdx.x;
    const int c = t & 63, rg = t >> 6;
    #pragma unroll 4
    for (int i = 0; i < 16; ++i) {
        int r = rg * 16 + i;
        size_t gi = (size_t)(k0 + r) * ldw + col0 + n0 + c;
        tile[r][c] = fmt ? f2b(((const float*)W)[gi]) : ((const u16*)W)[gi];
    }
    __syncthreads();
    #pragma unroll 4
    for (int i = 0; i < 16; ++i) {
        int r = rg * 16 + i;
        WT[(size_t)(n0 + r) * Kdim + k0 + c] = tile[c][r];
    }
}

// ---------------------------------------------------------------------------
// MFMA GEMM: C[m, j] = sum_k A[m,k] * BT[j,k]   (BT: n-major bf16)
// 128x128 tile, 4 waves (2x2), 4x4 x mfma_f32_16x16x32_bf16 per wave.
// ---------------------------------------------------------------------------
template<int RELU, int BIAS, int AEXT, int CEXT>
__global__ __launch_bounds__(256)
void gemm_mfma(const void* __restrict__ A, const u16* __restrict__ BT,
               void* __restrict__ Cout, const void* __restrict__ bias,
               const int* __restrict__ flag, int K, int ldc)
{
    __shared__ u16 As[128 * 32];
    __shared__ u16 Bs[128 * 32];
    const int fmt = flag[0];
    const int t    = threadIdx.x;
    const int lane = t & 63;
    const int w    = t >> 6;          // wave 0..3
    const int wm   = w >> 1, wn = w & 1;
    const int quad = lane >> 4;       // 0..3
    const int l16  = lane & 15;
    const int m0 = blockIdx.y * 128;
    const int j0 = blockIdx.x * 128;

    const int srow = lane >> 2;
    const int gseg = ((lane & 3) ^ ((lane >> 3) & 3)) * 8;

    f32x4 acc[4][4] = {};

    for (int k0 = 0; k0 < K; k0 += 32) {
        if (AEXT && fmt) {
            #pragma unroll
            for (int i = 0; i < 2; ++i) {
                const int r0 = w * 32 + i * 16;
                const float* gp = (const float*)A + (size_t)(m0 + r0 + srow) * K + k0 + gseg;
                float4 f0 = *(const float4*)gp;
                float4 f1 = *(const float4*)(gp + 4);
                union { bf16x8 v; u16 s[8]; } o;
                o.s[0] = f2b(f0.x); o.s[1] = f2b(f0.y); o.s[2] = f2b(f0.z); o.s[3] = f2b(f0.w);
                o.s[4] = f2b(f1.x); o.s[5] = f2b(f1.y); o.s[6] = f2b(f1.z); o.s[7] = f2b(f1.w);
                *(bf16x8*)&As[(r0 + srow) * 32 + (lane & 3) * 8] = o.v;
            }
        } else {
            #pragma unroll
            for (int i = 0; i < 2; ++i) {
                const int r0 = w * 32 + i * 16;
                const u16* gp = (const u16*)A + (size_t)(m0 + r0 + srow) * K + k0 + gseg;
                __builtin_amdgcn_global_load_lds(
                    (const __attribute__((address_space(1))) void*)gp,
                    (__attribute__((address_space(3))) void*)&As[r0 * 32], 16, 0, 0);
            }
        }
        #pragma unroll
        for (int i = 0; i < 2; ++i) {
            const int r0 = w * 32 + i * 16;
            const u16* gp = BT + (size_t)(j0 + r0 + srow) * K + k0 + gseg;
            __builtin_amdgcn_global_load_lds(
                (const __attribute__((address_space(1))) void*)gp,
                (__attribute__((address_space(3))) void*)&Bs[r0 * 32], 16, 0, 0);
        }
        __syncthreads();

        bf16x8 af[4], bfr[4];
        #pragma unroll
        for (int mt = 0; mt < 4; ++mt) {
            const int r = wm * 64 + mt * 16 + l16;
            const int slot = quad ^ ((r >> 1) & 3);
            af[mt] = *(const bf16x8*)&As[r * 32 + slot * 8];
        }
        #pragma unroll
        for (int nt = 0; nt < 4; ++nt) {
            const int r = wn * 64 + nt * 16 + l16;
            const int slot = quad ^ ((r >> 1) & 3);
            bfr[nt] = *(const bf16x8*)&Bs[r * 32 + slot * 8];
        }
        #pragma unroll
        for (int mt = 0; mt < 4; ++mt)
            #pragma unroll
            for (int nt = 0; nt < 4; ++nt)
                acc[mt][nt] = __builtin_amdgcn_mfma_f32_16x16x32_bf16(
                    af[mt], bfr[nt], acc[mt][nt], 0, 0, 0);
        __syncthreads();
    }

    #pragma unroll
    for (int mt = 0; mt < 4; ++mt) {
        #pragma unroll
        for (int nt = 0; nt < 4; ++nt) {
            const int col = j0 + wn * 64 + nt * 16 + l16;
            float bv = 0.f;
            if (BIAS) bv = fmt ? ((const float*)bias)[col] : b2f(((const u16*)bias)[col]);
            #pragma unroll
            for (int r = 0; r < 4; ++r) {
                const int row = m0 + wm * 64 + mt * 16 + quad * 4 + r;
                float v = acc[mt][nt][r];
                if (BIAS) v += bv;
                if (RELU) v = fmaxf(v, 0.f) + 1e-6f;
                if (CEXT && fmt) ((float*)Cout)[(size_t)row * ldc + col] = v;
                else             ((u16*)Cout)[(size_t)row * ldc + col] = f2b(v);
            }
        }
    }
}

// ---------------------------------------------------------------------------
// Fallback VALU GEMM (proven in R2) — used only if ws_size is too small.
// ---------------------------------------------------------------------------
template<int RELU, int BIAS, int AEXT, int CEXT>
__global__ __launch_bounds__(256)
void gemm_any(const void* __restrict__ A, const void* __restrict__ Bm,
              void* __restrict__ Cout, const void* __restrict__ bias,
              const int* __restrict__ flag,
              int M, int K, int ldb, int bcol0, int ldc)
{
    const int fmt = flag[0];
    __shared__ float As[16][128];
    __shared__ float Bs[16][128];
    const int t  = threadIdx.x;
    const int tx = t & 15, ty = t >> 4;
    const int m0 = blockIdx.y * 128;
    const int j0 = blockIdx.x * 128;
    const int la_row = t >> 1;
    const int la_k   = (t & 1) * 8;
    const int lb_k   = t >> 4;
    const int lb_j   = (t & 15) * 8;

    float acc[8][8];
    #pragma unroll
    for (int i = 0; i < 8; ++i)
        #pragma unroll
        for (int j = 0; j < 8; ++j) acc[i][j] = 0.f;

    for (int k0 = 0; k0 < K; k0 += 16) {
        float af[8], bfv[8];
        if (AEXT && fmt) {
            const float* ap = (const float*)A + (size_t)(m0 + la_row) * K + k0 + la_k;
            float4 a0 = *(const float4*)ap;
            float4 a1 = *(const float4*)(ap + 4);
            af[0] = a0.x; af[1] = a0.y; af[2] = a0.z; af[3] = a0.w;
            af[4] = a1.x; af[5] = a1.y; af[6] = a1.z; af[7] = a1.w;
        } else {
            uint4 av = *(const uint4*)((const u16*)A + (size_t)(m0 + la_row) * K + k0 + la_k);
            unpack8(av, af);
        }
        if (fmt) {
            const float* bp = (const float*)Bm + (size_t)(k0 + lb_k) * ldb + bcol0 + j0 + lb_j;
            float4 b0 = *(const float4*)bp;
            float4 b1 = *(const float4*)(bp + 4);
            bfv[0] = b0.x; bfv[1] = b0.y; bfv[2] = b0.z; bfv[3] = b0.w;
            bfv[4] = b1.x; bfv[5] = b1.y; bfv[6] = b1.z; bfv[7] = b1.w;
        } else {
            uint4 bv = *(const uint4*)((const u16*)Bm + (size_t)(k0 + lb_k) * ldb + bcol0 + j0 + lb_j);
            unpack8(bv, bfv);
        }
        __syncthreads();
        #pragma unroll
        for (int i = 0; i < 8; ++i) As[la_k + i][la_row] = af[i];
        *(float4*)&Bs[lb_k][lb_j]     = make_float4(bfv[0], bfv[1], bfv[2], bfv[3]);
        *(float4*)&Bs[lb_k][lb_j + 4] = make_float4(bfv[4], bfv[5], bfv[6], bfv[7]);
        __syncthreads();
        #pragma unroll
        for (int kk = 0; kk < 16; ++kk) {
            float a[8], b[8];
            *(float4*)&a[0] = *(const float4*)&As[kk][ty * 8];
            *(float4*)&a[4] = *(const float4*)&As[kk][ty * 8 + 4];
            *(float4*)&b[0] = *(const float4*)&Bs[kk][tx * 8];
            *(float4*)&b[4] = *(const float4*)&Bs[kk][tx * 8 + 4];
            #pragma unroll
            for (int i = 0; i < 8; ++i)
                #pragma unroll
                for (int j = 0; j < 8; ++j)
                    acc[i][j] += a[i] * b[j];
        }
    }

    #pragma unroll
    for (int i = 0; i < 8; ++i) {
        const int m = m0 + ty * 8 + i;
        float vals[8];
        #pragma unroll
        for (int j = 0; j < 8; ++j) {
            float v = acc[i][j];
            if (BIAS) {
                const int bi = j0 + tx * 8 + j;
                v += fmt ? ((const float*)bias)[bi] : b2f(((const u16*)bias)[bi]);
            }
            if (RELU) v = fmaxf(v, 0.f) + 1e-6f;
            vals[j] = v;
        }
        if (CEXT && fmt) {
            float* cp = (float*)Cout + (size_t)m * ldc + j0 + tx * 8;
            *(float4*)cp       = make_float4(vals[0], vals[1], vals[2], vals[3]);
            *(float4*)(cp + 4) = make_float4(vals[4], vals[5], vals[6], vals[7]);
        } else {
            union { uint4 v; u16 s[8]; } o;
            #pragma unroll
            for (int j = 0; j < 8; ++j) o.s[j] = f2b(vals[j]);
            *(uint4*)((u16*)Cout + (size_t)m * ldc + j0 + tx * 8) = o.v;
        }
    }
}

// k_mean[b, c] = mean_n k[b, n, c]
__global__ __launch_bounds__(256)
void kmean_kernel(const u16* __restrict__ k, float* __restrict__ km)
{
    const int c  = blockIdx.x * 256 + threadIdx.x;
    const int b  = blockIdx.y;
    const int nc = blockIdx.z;
    const u16* p = k + ((size_t)b * N_ + nc * 256) * C_ + c;
    float s = 0.f;
    for (int n = 0; n < 256; ++n) s += b2f(p[(size_t)n * C_]);
    atomicAdd(&km[b * C_ + c], s * (1.0f / N_));
}

// kvh[bh, d*64+e] += (1/N) * sum_{n in chunk} k*v
__global__ __launch_bounds__(256)
void kv_atomic(const u16* __restrict__ k, const u16* __restrict__ v,
               float* __restrict__ kvh)
{
    __shared__ float kk[4][64];
    __shared__ float vv[4][64];
    const int bh = blockIdx.x;
    const int ch = blockIdx.y;
    const int b = bh >> 4, h = bh & 15;
    const int t = threadIdx.x;
    const int e = t & 63, d0 = (t >> 6) * 16;
    const int lr = t >> 6, lc = t & 63;
    const int n0 = ch * 512;
    float acc[16];
    #pragma unroll
    for (int i = 0; i < 16; ++i) acc[i] = 0.f;

    for (int nb = 0; nb < 512; nb += 4) {
        size_t base = ((size_t)(b * N_ + n0 + nb + lr)) * C_ + h * 64 + lc;
        float kf = b2f(k[base]);
        float vf = b2f(v[base]);
        __syncthreads();
        kk[lr][lc] = kf;
        vv[lr][lc] = vf;
        __syncthreads();
        #pragma unroll
        for (int r = 0; r < 4; ++r) {
            float ve = vv[r][e];
            #pragma unroll
            for (int i = 0; i < 16; ++i) acc[i] += kk[r][d0 + i] * ve;
        }
    }
    float* dst = kvh + (size_t)bh * 4096;
    #pragma unroll
    for (int i = 0; i < 16; ++i)
        atomicAdd(&dst[(d0 + i) * 64 + e], acc[i] * (1.0f / N_));
}

// att (in-place safe over q; see R2)
__global__ __launch_bounds__(256)
void att_kernel(const u16* __restrict__ q, const float* __restrict__ kvh,
                const float* __restrict__ kmean, u16* __restrict__ y)
{
    __shared__ float kvs[64 * 64];
    __shared__ float qs[64 * 65];
    __shared__ float kmv[64];
    __shared__ float zs[64];
    const int bh = blockIdx.y;
    const int b = bh >> 4, h = bh & 15;
    const int n0 = blockIdx.x * 64;
    const int t = threadIdx.x;

    const float* kvsrc = kvh + (size_t)bh * 4096;
    for (int i = t; i < 4096; i += 256) kvs[i] = kvsrc[i];
    if (t < 64) kmv[t] = kmean[b * C_ + h * 64 + t];
    for (int i = t; i < 4096; i += 256) {
        int r = i >> 6, cq = i & 63;
        qs[r * 65 + cq] = b2f(q[((size_t)(b * N_ + n0 + r)) * C_ + h * 64 + cq]);
    }
    __syncthreads();
    if (t < 64) {
        float s = 1e-6f;
        #pragma unroll
        for (int d = 0; d < 64; ++d) s += qs[t * 65 + d] * kmv[d];
        zs[t] = 1.0f / s;
    }
    __syncthreads();
    const int e = t & 63, rg = t >> 6;
    for (int rr = 0; rr < 16; ++rr) {
        int r = rg * 16 + rr;
        float acc = 0.f;
        #pragma unroll
        for (int d = 0; d < 64; ++d) acc += qs[r * 65 + d] * kvs[d * 64 + e];
        y[((size_t)(b * N_ + n0 + r)) * C_ + h * 64 + e] = f2b(acc * zs[r]);
    }
}

// ---------------------------------------------------------------------------
// Depthwise 5x5 conv over v, add into y — channel-vectorized (uint4 = 8 bf16).
// Thread = 8 consecutive channels of one pixel. Wave-uniform pixel -> no
// divergence on border branches. Weights in LDS as wt[tap][64] -> 2 aligned
// ds_read_b128 per tap (2-way bank aliasing = free).
// ---------------------------------------------------------------------------
__global__ __launch_bounds__(256)
void conv_add(const u16* __restrict__ v, const void* __restrict__ w,
              const void* __restrict__ wb, u16* __restrict__ y,
              const int* __restrict__ flag)
{
    __shared__ float wt[25][64];
    __shared__ float bl[64];
    const int fmt = flag[0];
    const int t = threadIdx.x;
    for (int i = t; i < 1600; i += 256) {
        const int tap = i >> 6, c = i & 63;
        const int src = c * 25 + tap;
        wt[tap][c] = fmt ? ((const float*)w)[src] : b2f(((const u16*)w)[src]);
    }
    if (t < 64)
        bl[t] = fmt ? ((const float*)wb)[t] : b2f(((const u16*)wb)[t]);
    __syncthreads();

    const size_t gid = (size_t)blockIdx.x * 256 + t;   // 0 .. 2,097,151
    const int cg = (int)(gid & 127);                   // channel-group (8 ch)
    const int n  = (int)((gid >> 7) & 4095);           // pixel (wave-uniform)
    const int b  = (int)(gid >> 19);
    const int c0 = cg * 8;
    const int cb = c0 & 63;                            // weight channel base
    const int yp = n >> 6, xp = n & 63;

    float acc[8];
    #pragma unroll
    for (int j = 0; j < 8; ++j) acc[j] = bl[cb + j];

    const u16* vbase = v + (size_t)b * N_ * C_ + c0;
    #pragma unroll
    for (int dy = 0; dy < 5; ++dy) {
        const int yy = yp + dy - 2;
        if (yy < 0 || yy >= HW_) continue;
        #pragma unroll
        for (int dx = 0; dx < 5; ++dx) {
            const int xx = xp + dx - 2;
            if (xx < 0 || xx >= HW_) continue;
            uint4 pv = *(const uint4*)(vbase + (size_t)(yy * HW_ + xx) * C_);
            float f[8];
            unpack8(pv, f);
            const int tap = dy * 5 + dx;
            float4 w0 = *(const float4*)&wt[tap][cb];
            float4 w1 = *(const float4*)&wt[tap][cb + 4];
            acc[0] += w0.x * f[0]; acc[1] += w0.y * f[1];
            acc[2] += w0.z * f[2]; acc[3] += w0.w * f[3];
            acc[4] += w1.x * f[4]; acc[5] += w1.y * f[5];
            acc[6] += w1.z * f[6]; acc[7] += w1.w * f[7];
        }
    }

    uint4 yv = *(const uint4*)(y + gid * 8);
    float yf[8];
    unpack8(yv, yf);
    union { uint4 v4; u16 s[8]; } o;
    #pragma unroll
    for (int j = 0; j < 8; ++j) o.s[j] = f2b(yf[j] + acc[j]);
    *(uint4*)(y + gid * 8) = o.v4;
}

extern "C" void kernel_launch(void* const* d_in, const int* in_sizes, int n_in,
                              void* d_out, int out_size, void* d_ws, size_t ws_size,
                              hipStream_t stream)
{
    const void* x     = d_in[0];
    const void* Wq    = d_in[1];
    const void* Wkv   = d_in[2];
    const void* Wproj = d_in[3];
    const void* bproj = d_in[4];
    const void* dwc_w = d_in[5];
    const void* dwc_b = d_in[6];

    char* ws = (char*)d_ws;
    const size_t MI = 1024 * 1024;
    const size_t NEED_FAST = 35 * MI + 17 * 1024;

    if (ws_size >= NEED_FAST) {
        // ---- fast path (MFMA) ----
        u16*   vbuf  = (u16*)ws;
        u16*   WT    = (u16*)(ws + 32 * MI);
        float* kvh   = (float*)(ws + 34 * MI);
        float* kmean = (float*)(ws + 35 * MI);
        int*   flag  = (int*)(ws + 35 * MI + 16 * 1024);
        u16*   kq    = (u16*)d_out;
        u16*   ybuf  = (u16*)ws;

        detect_fmt<<<1, 256, 0, stream>>>((const u16*)x, flag);
        zero_f32<<<dim3(1040), 256, 0, stream>>>(kvh, 266240);   // kvh + kmean contiguous

        // v = x @ Wkv[:, C:]
        transpose_w<<<dim3(16, 16), 256, 0, stream>>>(Wkv, WT, flag, 2 * C_, C_, C_);
        gemm_mfma<0, 0, 1, 0><<<dim3(8, 128), 256, 0, stream>>>(x, WT, vbuf, nullptr, flag, C_, C_);
        // k = relu(x @ Wkv[:, :C]) + eps  -> d_out
        transpose_w<<<dim3(16, 16), 256, 0, stream>>>(Wkv, WT, flag, 2 * C_, 0, C_);
        gemm_mfma<1, 0, 1, 0><<<dim3(8, 128), 256, 0, stream>>>(x, WT, kq, nullptr, flag, C_, C_);

        kmean_kernel<<<dim3(4, B_, 16), 256, 0, stream>>>(kq, kmean);
        kv_atomic<<<dim3(64, 8), 256, 0, stream>>>(kq, vbuf, kvh);

        // q = relu(x @ Wq) + eps -> d_out (k dead)
        transpose_w<<<dim3(16, 16), 256, 0, stream>>>(Wq, WT, flag, C_, 0, C_);
        gemm_mfma<1, 0, 1, 0><<<dim3(8, 128), 256, 0, stream>>>(x, WT, kq, nullptr, flag, C_, C_);

        att_kernel<<<dim3(64, 64), 256, 0, stream>>>(kq, kvh, kmean, kq);
        conv_add<<<dim3(8192), 256, 0, stream>>>(vbuf, dwc_w, dwc_b, kq, flag);

        // move y into ws (v dead), then out = y @ Wproj + bproj
        hipMemcpyAsync(ws, d_out, (size_t)NT_ * C_ * sizeof(u16), hipMemcpyDeviceToDevice, stream);
        transpose_w<<<dim3(16, 16), 256, 0, stream>>>(Wproj, WT, flag, C_, 0, C_);
        gemm_mfma<0, 1, 0, 1><<<dim3(8, 128), 256, 0, stream>>>(ybuf, WT, d_out, bproj, flag, C_, C_);
    } else {
        // ---- fallback path (proven R2) ----
        u16*   vbuf  = (u16*)ws;
        float* kmean = (float*)(ws + 32 * MI);
        float* kvh   = (float*)(ws + 32 * MI + 16 * 1024);
        int*   flag  = (int*)(ws + 32 * MI + 16 * 1024 + 1 * MI);
        u16*   kq    = (u16*)d_out;
        u16*   ybuf  = (u16*)ws;

        detect_fmt<<<1, 256, 0, stream>>>((const u16*)x, flag);
        zero_f32<<<dim3(1040), 256, 0, stream>>>(kmean, 266240);

        gemm_any<0, 0, 1, 0><<<dim3(8, 128), 256, 0, stream>>>(x, Wkv, vbuf, nullptr, flag, NT_, C_, 2 * C_, C_, C_);
        gemm_any<1, 0, 1, 0><<<dim3(8, 128), 256, 0, stream>>>(x, Wkv, kq,   nullptr, flag, NT_, C_, 2 * C_, 0,  C_);

        kmean_kernel<<<dim3(4, B_, 16), 256, 0, stream>>>(kq, kmean);
        kv_atomic<<<dim3(64, 8), 256, 0, stream>>>(kq, vbuf, kvh);

        gemm_any<1, 0, 1, 0><<<dim3(8, 128), 256, 0, stream>>>(x, Wq, kq, nullptr, flag, NT_, C_, C_, 0, C_);

        att_kernel<<<dim3(64, 64), 256, 0, stream>>>(kq, kvh, kmean, kq);
        conv_add<<<dim3(8192), 256, 0, stream>>>(vbuf, dwc_w, dwc_b, kq, flag);

        hipMemcpyAsync(ws, d_out, (size_t)NT_ * C_ * sizeof(u16), hipMemcpyDeviceToDevice, stream);
        gemm_any<0, 1, 0, 1><<<dim3(8, 128), 256, 0, stream>>>(ybuf, Wproj, d_out, bproj, flag, NT_, C_, C_, 0, C_);
    }
}